// Round 7
// baseline (378.563 us; speedup 1.0000x reference)
//
#include <hip/hip_runtime.h>

// S4 layer: y = C * scan(a_bar, dt*B*u) + u*D
//   setup:    dt = mean(exp(log_dt)); A_bar = I + dt*A; B_hat = bf16(dt*B); C_hat = bf16(C)
//   matsq3x2: A_pow = A_bar^64 (two kernels, 3 squarings each)
//   gemm1:    bu[m][n] = sum_k u[m][k]*(dt*B)[n][k]   (MFMA bf16, M-tile 64, reg-pipelined)
//   scan<0>:  per-chunk local scan from zero -> chunk end states E  (2 tasks/wave)
//   combine:  S_{j+1} = A_pow * S_j + E_j
//   scan<1>:  re-run recurrence with true initial states; writes xs as bf16
//   gemm2:    y[m][d] = sum_n xs[m][n]*C[d][n] + u[m][d]*D[d]  (MFMA bf16, 128x128 tile)

#define DM   1024
#define DS   64
#define NB   16
#define LL   4096
#define LC   64
#define NCH  (LL / LC)     // 64
#define MTOT (NB * LL)     // 65536
#define NTASK (NB * NCH)   // 1024

// workspace layout in floats
#define WS_ABAR 64
#define WS_APOW (WS_ABAR + 4096)          // 4160
#define WS_TMP  (WS_APOW + 4096)          // 8256
#define WS_E    (WS_TMP + 4096)           // 12352
#define WS_S    (WS_E + NTASK * DS)       // 77888
#define WS_BHI  143424                    // 65536 ushort = 32768 floats
#define WS_CHI  (WS_BHI + 32768)          // 176192
#define WS_XS   (WS_CHI + 32768)          // 208960: 4194304 ushort = 2097152 floats
#define WS_BU   (WS_XS + 2097152)         // 2306112
// total = 2306112 + 4194304 floats ~= 26 MB (ws allocation is ~1 GiB per harness fill)

typedef __attribute__((ext_vector_type(4))) float f32x4;
typedef __attribute__((ext_vector_type(8))) short bf16x8;
typedef __attribute__((ext_vector_type(8))) unsigned short ushort8;

__device__ inline unsigned short bf16_rne(float f) {
    unsigned u = __builtin_bit_cast(unsigned, f);
    u += 0x7FFFu + ((u >> 16) & 1u);
    return (unsigned short)(u >> 16);
}

// ---------------- setup: dt + A_bar + B_hat + C_hat in one launch ----------------
// blocks 0..63: B_hat = bf16(dt*B); 64..127: C_hat = bf16(C); 128: A_bar + ws[0].
// Every block recomputes dt with the identical reduction order (bit-stable).
__global__ __launch_bounds__(256) void k_setup(const float* __restrict__ A,
                                               const float* __restrict__ Bm,
                                               const float* __restrict__ C,
                                               const float* __restrict__ log_dt,
                                               float* __restrict__ ws) {
    __shared__ float red[256];
    int tid = threadIdx.x;
    int bid = blockIdx.x;
    float s = 0.f;
    for (int i = tid; i < DM; i += 256) s += expf(log_dt[i]);
    red[tid] = s;
    __syncthreads();
    for (int off = 128; off > 0; off >>= 1) {
        if (tid < off) red[tid] += red[tid + off];
        __syncthreads();
    }
    float dt = red[0] * (1.f / (float)DM);

    if (bid < 128) {
        int isC = bid >> 6;
        const float* src = isC ? C : Bm;
        unsigned short* dst = (unsigned short*)(ws + (isC ? WS_CHI : WS_BHI));
        float scale = isC ? 1.f : dt;
        int i = ((bid & 63) * 256 + tid) * 4;
        float4 v = *reinterpret_cast<const float4*>(&src[i]);
        ushort4 h;
        h.x = bf16_rne(v.x * scale);
        h.y = bf16_rne(v.y * scale);
        h.z = bf16_rne(v.z * scale);
        h.w = bf16_rne(v.w * scale);
        *reinterpret_cast<ushort4*>(&dst[i]) = h;
    } else {
        if (tid == 0) ws[0] = dt;
        for (int idx = tid; idx < 4096; idx += 256) {
            int n = idx >> 6, m = idx & 63;
            ws[WS_ABAR + idx] = dt * A[idx] + ((n == m) ? 1.f : 0.f);
        }
    }
}

// ---------------- matsq3: dst = src^8 (3 squarings). grid=16 x 256 ----------------
// Stages 1-2 computed full-matrix (redundant per block) in LDS ping-pong;
// stage 3 writes only this block's 4 rows.
__global__ __launch_bounds__(256) void k_matsq3(const float* __restrict__ src,
                                                float* __restrict__ dst) {
    __shared__ float s0[64][65], s1[64][65];
    int tid = threadIdx.x;
#pragma unroll
    for (int rep = 0; rep < 16; ++rep) {
        int idx = rep * 256 + tid;
        s0[idx >> 6][idx & 63] = src[idx];
    }
    __syncthreads();
#pragma unroll 1
    for (int st = 0; st < 2; ++st) {
        float (*S)[65] = st ? s1 : s0;
        float (*D)[65] = st ? s0 : s1;
#pragma unroll
        for (int rep = 0; rep < 16; ++rep) {
            int idx = rep * 256 + tid;
            int n = idx >> 6, m = idx & 63;   // n wave-uniform
            float a0 = 0.f, a1 = 0.f, a2 = 0.f, a3 = 0.f;
#pragma unroll
            for (int k = 0; k < 64; k += 4) {
                a0 = fmaf(S[n][k + 0], S[k + 0][m], a0);
                a1 = fmaf(S[n][k + 1], S[k + 1][m], a1);
                a2 = fmaf(S[n][k + 2], S[k + 2][m], a2);
                a3 = fmaf(S[n][k + 3], S[k + 3][m], a3);
            }
            D[n][m] = (a0 + a1) + (a2 + a3);
        }
        __syncthreads();
    }
    // after 2 stages the current matrix is in s0; final squaring -> dst rows
    int n = (blockIdx.x << 2) + (tid >> 6);  // wave-uniform row
    int m = tid & 63;
    float a0 = 0.f, a1 = 0.f, a2 = 0.f, a3 = 0.f;
#pragma unroll
    for (int k = 0; k < 64; k += 4) {
        a0 = fmaf(s0[n][k + 0], s0[k + 0][m], a0);
        a1 = fmaf(s0[n][k + 1], s0[k + 1][m], a1);
        a2 = fmaf(s0[n][k + 2], s0[k + 2][m], a2);
        a3 = fmaf(s0[n][k + 3], s0[k + 3][m], a3);
    }
    dst[(n << 6) + m] = (a0 + a1) + (a2 + a3);
}

// ---------------- GEMM1: bu = u @ (dt*B)^T  (M=65536,K=1024,N=64) ----------------
// M-tile 64 (grid 1024 = 4 blocks/CU), single bf16, register-prefetch pipeline.
__global__ __launch_bounds__(256, 4) void k_gemm1(const float* __restrict__ u,
                                                  const float* __restrict__ ws,
                                                  float* __restrict__ bu) {
    __shared__ short a_t[64][72];    // 9216 B
    __shared__ short b_t[64][72];    // 9216 B
    const unsigned short* bhig = (const unsigned short*)(ws + WS_BHI);
    int tid = threadIdx.x;
    int m0 = blockIdx.x * 64;
    int wid = tid >> 6, lane = tid & 63;
    int lr = lane & 15, lg = lane >> 4;
    int sr = tid >> 3, sc8 = (tid & 7) << 3;
    int bn = tid >> 3, bk8 = (tid & 7) << 3;

    f32x4 acc[4];
#pragma unroll
    for (int j = 0; j < 4; ++j) acc[j] = (f32x4)(0.f);

    float4 ra[2][2];
    ushort8 rb[2];
#pragma unroll
    for (int i = 0; i < 2; ++i) {
        ra[i][0] = *reinterpret_cast<const float4*>(&u[(size_t)(m0 + sr + 32 * i) * DM + sc8]);
        ra[i][1] = *reinterpret_cast<const float4*>(&u[(size_t)(m0 + sr + 32 * i) * DM + sc8 + 4]);
    }
#pragma unroll
    for (int j = 0; j < 2; ++j)
        rb[j] = *reinterpret_cast<const ushort8*>(&bhig[(size_t)(bn + 32 * j) * DM + bk8]);

    for (int kt = 0; kt < 16; ++kt) {
#pragma unroll
        for (int i = 0; i < 2; ++i) {
            ushort8 h;
            h[0] = bf16_rne(ra[i][0].x); h[1] = bf16_rne(ra[i][0].y);
            h[2] = bf16_rne(ra[i][0].z); h[3] = bf16_rne(ra[i][0].w);
            h[4] = bf16_rne(ra[i][1].x); h[5] = bf16_rne(ra[i][1].y);
            h[6] = bf16_rne(ra[i][1].z); h[7] = bf16_rne(ra[i][1].w);
            *reinterpret_cast<ushort8*>(&a_t[sr + 32 * i][sc8]) = h;
        }
#pragma unroll
        for (int j = 0; j < 2; ++j)
            *reinterpret_cast<ushort8*>(&b_t[bn + 32 * j][bk8]) = rb[j];
        __syncthreads();
        if (kt + 1 < 16) {
            int k0n = (kt + 1) * 64;
#pragma unroll
            for (int i = 0; i < 2; ++i) {
                ra[i][0] = *reinterpret_cast<const float4*>(&u[(size_t)(m0 + sr + 32 * i) * DM + k0n + sc8]);
                ra[i][1] = *reinterpret_cast<const float4*>(&u[(size_t)(m0 + sr + 32 * i) * DM + k0n + sc8 + 4]);
            }
#pragma unroll
            for (int j = 0; j < 2; ++j)
                rb[j] = *reinterpret_cast<const ushort8*>(&bhig[(size_t)(bn + 32 * j) * DM + k0n + bk8]);
        }
#pragma unroll
        for (int kf = 0; kf < 2; ++kf) {
            int kb = kf * 32 + lg * 8;
            bf16x8 af = *reinterpret_cast<bf16x8*>(&a_t[wid * 16 + lr][kb]);
#pragma unroll
            for (int nf = 0; nf < 4; ++nf) {
                bf16x8 bf_ = *reinterpret_cast<bf16x8*>(&b_t[nf * 16 + lr][kb]);
                acc[nf] = __builtin_amdgcn_mfma_f32_16x16x32_bf16(af, bf_, acc[nf], 0, 0, 0);
            }
        }
        __syncthreads();
    }
#pragma unroll
    for (int nf = 0; nf < 4; ++nf)
#pragma unroll
        for (int q = 0; q < 4; ++q) {
            size_t row = (size_t)(m0 + wid * 16 + lg * 4 + q);
            bu[row * DS + nf * 16 + lr] = acc[nf][q];
        }
}

// ---------------- chunked scan: 2 independent tasks per wave ----------------
// Unconditional next-step prefetch: at t=LC-1 reads 256 B past the chunk, which is
// in-bounds of the ~1 GiB ws allocation (value never used).
template <int PASS>
__global__ __launch_bounds__(256) void k_scan(float* __restrict__ ws) {
    const float* Abar = ws + WS_ABAR;
    float* bu = ws + WS_BU;
    unsigned short* xs = (unsigned short*)(ws + WS_XS);
    int tid = threadIdx.x;
    int w = tid >> 6, lane = tid & 63;
    int t0 = blockIdx.x * 4 + w;            // 0..511
    int t1 = t0 + 512;                      // 512..1023
    __shared__ float xbuf[4][2][64];

    float a_row[64];
#pragma unroll
    for (int mg = 0; mg < 16; ++mg) {
        float4 v = *reinterpret_cast<const float4*>(&Abar[lane * 64 + mg * 4]);
        a_row[mg * 4 + 0] = v.x; a_row[mg * 4 + 1] = v.y;
        a_row[mg * 4 + 2] = v.z; a_row[mg * 4 + 3] = v.w;
    }
    float x0, x1;
    if (PASS == 0) { x0 = 0.f; x1 = 0.f; }
    else {
        x0 = ws[WS_S + (size_t)t0 * DS + lane];
        x1 = ws[WS_S + (size_t)t1 * DS + lane];
    }
    size_t r0 = (size_t)(t0 >> 6) * LL + (size_t)(t0 & 63) * LC;
    size_t r1 = (size_t)(t1 >> 6) * LL + (size_t)(t1 & 63) * LC;
    float* bub0 = bu + r0 * DS;
    float* bub1 = bu + r1 * DS;
    unsigned short* xp0 = xs + r0 * DS;
    unsigned short* xp1 = xs + r1 * DS;
    float v0 = bub0[lane], v1 = bub1[lane];
    for (int t = 0; t < LC; ++t) {
        float n0 = bub0[(t + 1) * DS + lane];   // prefetch (last iter value unused)
        float n1 = bub1[(t + 1) * DS + lane];
        xbuf[w][0][lane] = x0;
        xbuf[w][1][lane] = x1;
        asm volatile("" ::: "memory");
        float p0[4], p1[4];
#pragma unroll
        for (int g = 0; g < 4; ++g) {
            float acc0 = (g == 0) ? v0 : 0.f;
            float acc1 = (g == 0) ? v1 : 0.f;
#pragma unroll
            for (int q = 0; q < 4; ++q) {
                float4 m0v = *reinterpret_cast<float4*>(&xbuf[w][0][g * 16 + q * 4]);
                float4 m1v = *reinterpret_cast<float4*>(&xbuf[w][1][g * 16 + q * 4]);
                float c0 = a_row[g * 16 + q * 4 + 0], c1 = a_row[g * 16 + q * 4 + 1];
                float c2 = a_row[g * 16 + q * 4 + 2], c3 = a_row[g * 16 + q * 4 + 3];
                acc0 = fmaf(c0, m0v.x, acc0); acc1 = fmaf(c0, m1v.x, acc1);
                acc0 = fmaf(c1, m0v.y, acc0); acc1 = fmaf(c1, m1v.y, acc1);
                acc0 = fmaf(c2, m0v.z, acc0); acc1 = fmaf(c2, m1v.z, acc1);
                acc0 = fmaf(c3, m0v.w, acc0); acc1 = fmaf(c3, m1v.w, acc1);
            }
            p0[g] = acc0; p1[g] = acc1;
        }
        asm volatile("" ::: "memory");
        x0 = (p0[0] + p0[1]) + (p0[2] + p0[3]);
        x1 = (p1[0] + p1[1]) + (p1[2] + p1[3]);
        if (PASS == 1) {
            xp0[t * DS + lane] = bf16_rne(x0);
            xp1[t * DS + lane] = bf16_rne(x1);
        }
        v0 = n0; v1 = n1;
    }
    if (PASS == 0) {
        ws[WS_E + (size_t)t0 * DS + lane] = x0;
        ws[WS_E + (size_t)t1 * DS + lane] = x1;
    }
}

// ---------------- sequential chunk-boundary propagation ----------------
__global__ __launch_bounds__(64) void k_combine(float* __restrict__ ws) {
    const float* Apow = ws + WS_APOW;
    int b = blockIdx.x;
    int lane = threadIdx.x;
    __shared__ float xbuf[64];
    __shared__ float e_lds[NCH][64];         // 16 KB: all E for this batch
    const float* Eb = ws + WS_E + (size_t)b * NCH * DS;
#pragma unroll
    for (int r = 0; r < 16; ++r) {
        int idx = r * 64 + lane;
        int jj = idx >> 4, c4 = (idx & 15) << 2;
        *reinterpret_cast<float4*>(&e_lds[jj][c4]) =
            *reinterpret_cast<const float4*>(&Eb[jj * DS + c4]);
    }
    float p_row[64];
#pragma unroll
    for (int mg = 0; mg < 16; ++mg) {
        float4 v = *reinterpret_cast<const float4*>(&Apow[lane * 64 + mg * 4]);
        p_row[mg * 4 + 0] = v.x; p_row[mg * 4 + 1] = v.y;
        p_row[mg * 4 + 2] = v.z; p_row[mg * 4 + 3] = v.w;
    }
    __syncthreads();
    float x = 0.f;
    for (int jj = 0; jj < NCH; ++jj) {
        size_t task = (size_t)b * NCH + jj;
        ws[WS_S + task * DS + lane] = x;
        float e = e_lds[jj][lane];
        xbuf[lane] = x;
        asm volatile("" ::: "memory");
        float part[4];
#pragma unroll
        for (int g = 0; g < 4; ++g) {
            float acc = (g == 0) ? e : 0.f;
#pragma unroll
            for (int q = 0; q < 4; ++q) {
                float4 xm = *reinterpret_cast<float4*>(&xbuf[g * 16 + q * 4]);
                acc = fmaf(p_row[g * 16 + q * 4 + 0], xm.x, acc);
                acc = fmaf(p_row[g * 16 + q * 4 + 1], xm.y, acc);
                acc = fmaf(p_row[g * 16 + q * 4 + 2], xm.z, acc);
                acc = fmaf(p_row[g * 16 + q * 4 + 3], xm.w, acc);
            }
            part[g] = acc;
        }
        asm volatile("" ::: "memory");
        x = (part[0] + part[1]) + (part[2] + part[3]);
    }
}

// ---------------- GEMM2: y = xs @ C^T + u*D  (M=65536,K=64,N=1024) ----------------
// M-tile 128, N-tile 128, single bf16, 36.8 KB LDS (epilogue reuses tiles in 2 halves).
__global__ __launch_bounds__(256, 4) void k_gemm2(const float* __restrict__ u,
                                                  const float* __restrict__ Dv,
                                                  const float* __restrict__ ws,
                                                  float* __restrict__ y) {
    __shared__ __align__(16) char smem[2 * 128 * 72 * 2];   // 36864 B
    short (*a_t)[72] = (short(*)[72])(smem);
    short (*c_t)[72] = (short(*)[72])(smem + 18432);
    float (*out_lds)[132] = (float(*)[132])(smem);          // 33792 B reused per half

    const unsigned short* xsb = (const unsigned short*)(ws + WS_XS);
    const unsigned short* chig = (const unsigned short*)(ws + WS_CHI);
    int tid = threadIdx.x;
    int m0 = blockIdx.x * 128;
    int d0 = blockIdx.y * 128;
    int wid = tid >> 6, lane = tid & 63;
    int lr = lane & 15, lg = lane >> 4;

#pragma unroll
    for (int rep = 0; rep < 4; ++rep) {            // stage xs tile 128x64 bf16
        int idx = rep * 256 + tid;
        int r = idx >> 3, k8 = (idx & 7) << 3;
        *reinterpret_cast<ushort8*>(&a_t[r][k8]) =
            *reinterpret_cast<const ushort8*>(&xsb[(size_t)(m0 + r) * DS + k8]);
    }
#pragma unroll
    for (int rep = 0; rep < 4; ++rep) {            // stage C tile 128x64 bf16
        int idx = rep * 256 + tid;
        int dl = idx >> 3, n8 = (idx & 7) << 3;
        *reinterpret_cast<ushort8*>(&c_t[dl][n8]) =
            *reinterpret_cast<const ushort8*>(&chig[(size_t)(d0 + dl) * DS + n8]);
    }
    __syncthreads();

    f32x4 acc[2][8];
#pragma unroll
    for (int i = 0; i < 2; ++i)
#pragma unroll
        for (int j = 0; j < 8; ++j) acc[i][j] = (f32x4)(0.f);

#pragma unroll
    for (int kf = 0; kf < 2; ++kf) {
        int kb = kf * 32 + lg * 8;
        bf16x8 ah0 = *reinterpret_cast<bf16x8*>(&a_t[wid * 32 + lr][kb]);
        bf16x8 ah1 = *reinterpret_cast<bf16x8*>(&a_t[wid * 32 + 16 + lr][kb]);
#pragma unroll
        for (int nf = 0; nf < 8; ++nf) {
            bf16x8 cb = *reinterpret_cast<bf16x8*>(&c_t[nf * 16 + lr][kb]);
            acc[0][nf] = __builtin_amdgcn_mfma_f32_16x16x32_bf16(ah0, cb, acc[0][nf], 0, 0, 0);
            acc[1][nf] = __builtin_amdgcn_mfma_f32_16x16x32_bf16(ah1, cb, acc[1][nf], 0, 0, 0);
        }
    }
    __syncthreads();   // all fragment reads done; smem now reusable

#pragma unroll
    for (int h = 0; h < 2; ++h) {
        if ((wid >> 1) == h) {
            int rbase = (wid & 1) * 32;
#pragma unroll
            for (int mf = 0; mf < 2; ++mf)
#pragma unroll
                for (int nf = 0; nf < 8; ++nf)
#pragma unroll
                    for (int q = 0; q < 4; ++q)
                        out_lds[rbase + mf * 16 + lg * 4 + q][nf * 16 + lr] = acc[mf][nf][q];
        }
        __syncthreads();
#pragma unroll
        for (int rep = 0; rep < 8; ++rep) {        // coalesced float4 stores
            int idx = rep * 256 + tid;
            int r = idx >> 5, c4 = (idx & 31) << 2;
            float4 a = *reinterpret_cast<float4*>(&out_lds[r][c4]);
            size_t row = (size_t)(m0 + h * 64 + r);
            int c = d0 + c4;
            float4 uv = *reinterpret_cast<const float4*>(&u[row * DM + c]);
            float4 dv = *reinterpret_cast<const float4*>(&Dv[c]);
            float4 o;
            o.x = a.x + uv.x * dv.x;
            o.y = a.y + uv.y * dv.y;
            o.z = a.z + uv.z * dv.z;
            o.w = a.w + uv.w * dv.w;
            *reinterpret_cast<float4*>(&y[row * DM + c]) = o;
        }
        if (h == 0) __syncthreads();
    }
}

extern "C" void kernel_launch(void* const* d_in, const int* in_sizes, int n_in,
                              void* d_out, int out_size, void* d_ws, size_t ws_size,
                              hipStream_t stream) {
    (void)in_sizes; (void)n_in; (void)out_size; (void)ws_size;
    const float* u      = (const float*)d_in[0];
    const float* A      = (const float*)d_in[1];
    const float* Bm     = (const float*)d_in[2];
    const float* C      = (const float*)d_in[3];
    const float* Dv     = (const float*)d_in[4];
    const float* log_dt = (const float*)d_in[5];
    float* y  = (float*)d_out;
    float* ws = (float*)d_ws;
    float* bu = ws + WS_BU;

    k_setup<<<dim3(129), dim3(256), 0, stream>>>(A, Bm, C, log_dt, ws);
    k_matsq3<<<dim3(16), dim3(256), 0, stream>>>(ws + WS_ABAR, ws + WS_TMP);   // A^8
    k_matsq3<<<dim3(16), dim3(256), 0, stream>>>(ws + WS_TMP,  ws + WS_APOW);  // A^64

    k_gemm1<<<dim3(MTOT / 64), dim3(256), 0, stream>>>(u, ws, bu);
    k_scan<0><<<dim3(NTASK / 8), dim3(256), 0, stream>>>(ws);
    k_combine<<<dim3(NB), dim3(64), 0, stream>>>(ws);
    k_scan<1><<<dim3(NTASK / 8), dim3(256), 0, stream>>>(ws);
    k_gemm2<<<dim3(MTOT / 128, DM / 128), dim3(256), 0, stream>>>(u, Dv, ws, y);
}

// Round 8
// 336.797 us; speedup vs baseline: 1.1240x; 1.1240x over previous
//
#include <hip/hip_runtime.h>

// S4 layer: y = C * scan(a_bar, dt*B*u) + u*D
//   prep:     dt = mean(exp(log_dt)); A_bar = I + dt*A
//   cvt:      B_hat = bf16(dt*B), C_hat = bf16(C)
//   matsq x6: A2 = A_bar^2 (kept for scan); chain continues to A_pow = A_bar^64
//   gemm1:    bu[m][n] = sum_k u[m][k]*(dt*B)[n][k]   (MFMA bf16, M-tile 64, reg-pipelined)
//   scan<0>:  per-chunk DOUBLE-STEP scan from zero -> chunk end states E (1 task/wave)
//   combine:  S_{j+1} = A_pow * S_j + E_j
//   scan<1>:  re-run recurrence (double-step, odd states via A-dot); writes xs as bf16
//   gemm2:    y[m][d] = sum_n xs[m][n]*C[d][n] + u[m][d]*D[d]  (MFMA bf16, 128x128 tile)

#define DM   1024
#define DS   64
#define NB   16
#define LL   4096
#define LC   64
#define NCH  (LL / LC)     // 64
#define MTOT (NB * LL)     // 65536
#define NTASK (NB * NCH)   // 1024

// workspace layout in floats
#define WS_ABAR 64
#define WS_A2   4160
#define WS_APOW 8256
#define WS_TMP  12352
#define WS_E    16448
#define WS_S    (WS_E + NTASK * DS)       // 81984
#define WS_BHI  (WS_S + NTASK * DS)       // 147520
#define WS_CHI  (WS_BHI + 32768)          // 180288
#define WS_XS   (WS_CHI + 32768)          // 213056
#define WS_BU   (WS_XS + 2097152)         // 2310208
// total = 2310208 + 4194304 floats ~= 26 MB (ws allocation ~1 GiB per harness fill)

typedef __attribute__((ext_vector_type(4))) float f32x4;
typedef __attribute__((ext_vector_type(8))) short bf16x8;
typedef __attribute__((ext_vector_type(8))) unsigned short ushort8;

__device__ inline unsigned short bf16_rne(float f) {
    unsigned u = __builtin_bit_cast(unsigned, f);
    u += 0x7FFFu + ((u >> 16) & 1u);
    return (unsigned short)(u >> 16);
}

// ---------------- prep: dt + A_bar ----------------
__global__ __launch_bounds__(256) void k_prep(const float* __restrict__ A,
                                              const float* __restrict__ log_dt,
                                              float* __restrict__ ws) {
    __shared__ float red[256];
    int tid = threadIdx.x;
    float s = 0.f;
    for (int i = tid; i < DM; i += 256) s += expf(log_dt[i]);
    red[tid] = s;
    __syncthreads();
    for (int off = 128; off > 0; off >>= 1) {
        if (tid < off) red[tid] += red[tid + off];
        __syncthreads();
    }
    float dt = red[0] * (1.f / (float)DM);
    if (tid == 0) ws[0] = dt;
    for (int idx = tid; idx < 4096; idx += 256) {
        int n = idx >> 6, m = idx & 63;
        ws[WS_ABAR + idx] = dt * A[idx] + ((n == m) ? 1.f : 0.f);
    }
}

// ---------------- cvt: B (scaled by dt) and C -> bf16, one launch ----------------
__global__ __launch_bounds__(256) void k_cvt(const float* __restrict__ Bm,
                                             const float* __restrict__ C,
                                             float* __restrict__ ws) {
    int bid = blockIdx.x;
    int isC = bid >> 6;                      // blocks 0..63: B, 64..127: C
    const float* src = isC ? C : Bm;
    unsigned short* dst = (unsigned short*)(ws + (isC ? WS_CHI : WS_BHI));
    float scale = isC ? 1.f : ws[0];
    int i = ((bid & 63) * 256 + threadIdx.x) * 4;
    float4 v = *reinterpret_cast<const float4*>(&src[i]);
    ushort4 h;
    h.x = bf16_rne(v.x * scale);
    h.y = bf16_rne(v.y * scale);
    h.z = bf16_rne(v.z * scale);
    h.w = bf16_rne(v.w * scale);
    *reinterpret_cast<ushort4*>(&dst[i]) = h;
}

// dst = src*src for a 64x64 matrix. grid=16 blocks x 256 thr.
__global__ __launch_bounds__(256) void k_matsq(const float* __restrict__ src,
                                               float* __restrict__ dst) {
    __shared__ float s[64][65];
    int tid = threadIdx.x;
#pragma unroll
    for (int rep = 0; rep < 16; ++rep) {
        int idx = rep * 256 + tid;
        s[idx >> 6][idx & 63] = src[idx];
    }
    __syncthreads();
    int n = (blockIdx.x << 2) + (tid >> 6);  // wave-uniform row
    int m = tid & 63;
    float a0 = 0.f, a1 = 0.f, a2 = 0.f, a3 = 0.f;
#pragma unroll
    for (int k = 0; k < 64; k += 4) {
        a0 = fmaf(s[n][k + 0], s[k + 0][m], a0);
        a1 = fmaf(s[n][k + 1], s[k + 1][m], a1);
        a2 = fmaf(s[n][k + 2], s[k + 2][m], a2);
        a3 = fmaf(s[n][k + 3], s[k + 3][m], a3);
    }
    dst[(n << 6) + m] = (a0 + a1) + (a2 + a3);
}

// ---------------- GEMM1: bu = u @ (dt*B)^T  (M=65536,K=1024,N=64) ----------------
// M-tile 64 (grid 1024 = 4 blocks/CU), single bf16, register-prefetch pipeline.
__global__ __launch_bounds__(256, 4) void k_gemm1(const float* __restrict__ u,
                                                  const float* __restrict__ ws,
                                                  float* __restrict__ bu) {
    __shared__ short a_t[64][72];    // 9216 B
    __shared__ short b_t[64][72];    // 9216 B
    const unsigned short* bhig = (const unsigned short*)(ws + WS_BHI);
    int tid = threadIdx.x;
    int m0 = blockIdx.x * 64;
    int wid = tid >> 6, lane = tid & 63;
    int lr = lane & 15, lg = lane >> 4;
    int sr = tid >> 3, sc8 = (tid & 7) << 3;
    int bn = tid >> 3, bk8 = (tid & 7) << 3;

    f32x4 acc[4];
#pragma unroll
    for (int j = 0; j < 4; ++j) acc[j] = (f32x4)(0.f);

    float4 ra[2][2];
    ushort8 rb[2];
#pragma unroll
    for (int i = 0; i < 2; ++i) {
        ra[i][0] = *reinterpret_cast<const float4*>(&u[(size_t)(m0 + sr + 32 * i) * DM + sc8]);
        ra[i][1] = *reinterpret_cast<const float4*>(&u[(size_t)(m0 + sr + 32 * i) * DM + sc8 + 4]);
    }
#pragma unroll
    for (int j = 0; j < 2; ++j)
        rb[j] = *reinterpret_cast<const ushort8*>(&bhig[(size_t)(bn + 32 * j) * DM + bk8]);

    for (int kt = 0; kt < 16; ++kt) {
#pragma unroll
        for (int i = 0; i < 2; ++i) {
            ushort8 h;
            h[0] = bf16_rne(ra[i][0].x); h[1] = bf16_rne(ra[i][0].y);
            h[2] = bf16_rne(ra[i][0].z); h[3] = bf16_rne(ra[i][0].w);
            h[4] = bf16_rne(ra[i][1].x); h[5] = bf16_rne(ra[i][1].y);
            h[6] = bf16_rne(ra[i][1].z); h[7] = bf16_rne(ra[i][1].w);
            *reinterpret_cast<ushort8*>(&a_t[sr + 32 * i][sc8]) = h;
        }
#pragma unroll
        for (int j = 0; j < 2; ++j)
            *reinterpret_cast<ushort8*>(&b_t[bn + 32 * j][bk8]) = rb[j];
        __syncthreads();
        if (kt + 1 < 16) {
            int k0n = (kt + 1) * 64;
#pragma unroll
            for (int i = 0; i < 2; ++i) {
                ra[i][0] = *reinterpret_cast<const float4*>(&u[(size_t)(m0 + sr + 32 * i) * DM + k0n + sc8]);
                ra[i][1] = *reinterpret_cast<const float4*>(&u[(size_t)(m0 + sr + 32 * i) * DM + k0n + sc8 + 4]);
            }
#pragma unroll
            for (int j = 0; j < 2; ++j)
                rb[j] = *reinterpret_cast<const ushort8*>(&bhig[(size_t)(bn + 32 * j) * DM + k0n + bk8]);
        }
#pragma unroll
        for (int kf = 0; kf < 2; ++kf) {
            int kb = kf * 32 + lg * 8;
            bf16x8 af = *reinterpret_cast<bf16x8*>(&a_t[wid * 16 + lr][kb]);
#pragma unroll
            for (int nf = 0; nf < 4; ++nf) {
                bf16x8 bf_ = *reinterpret_cast<bf16x8*>(&b_t[nf * 16 + lr][kb]);
                acc[nf] = __builtin_amdgcn_mfma_f32_16x16x32_bf16(af, bf_, acc[nf], 0, 0, 0);
            }
        }
        __syncthreads();
    }
#pragma unroll
    for (int nf = 0; nf < 4; ++nf)
#pragma unroll
        for (int q = 0; q < 4; ++q) {
            size_t row = (size_t)(m0 + wid * 16 + lg * 4 + q);
            bu[row * DS + nf * 16 + lr] = acc[nf][q];
        }
}

// ---------------- chunked scan, DOUBLE-STEP: 1 task per wave, 1024 waves ----------------
// x_{2i+1} = A x_{2i} + b_{2i}            (pass1 only, same f32 order as before)
// x_{2i+2} = A2 x_{2i} + (A b_{2i} + b_{2i+1})
// b-broadcast double-buffered in LDS, written one iteration ahead.
// Prefetches read up to 512 B past the chunk (in-bounds of ~1 GiB ws).
template <int PASS>
__global__ __launch_bounds__(256) void k_scan(float* __restrict__ ws) {
    const float* Abar = ws + WS_ABAR;
    const float* A2m  = ws + WS_A2;
    float* bu = ws + WS_BU;
    unsigned short* xs = (unsigned short*)(ws + WS_XS);
    int tid = threadIdx.x;
    int w = tid >> 6, lane = tid & 63;
    int task = blockIdx.x * 4 + w;          // 0..1023
    __shared__ float xbuf[4][64];
    __shared__ float bbuf[4][2][64];

    float a_row[64], a2_row[64];
#pragma unroll
    for (int mg = 0; mg < 16; ++mg) {
        float4 v = *reinterpret_cast<const float4*>(&Abar[lane * 64 + mg * 4]);
        a_row[mg * 4 + 0] = v.x; a_row[mg * 4 + 1] = v.y;
        a_row[mg * 4 + 2] = v.z; a_row[mg * 4 + 3] = v.w;
        float4 v2 = *reinterpret_cast<const float4*>(&A2m[lane * 64 + mg * 4]);
        a2_row[mg * 4 + 0] = v2.x; a2_row[mg * 4 + 1] = v2.y;
        a2_row[mg * 4 + 2] = v2.z; a2_row[mg * 4 + 3] = v2.w;
    }
    float x;
    if (PASS == 0) x = 0.f;
    else           x = ws[WS_S + (size_t)task * DS + lane];

    size_t r0 = (size_t)(task >> 6) * LL + (size_t)(task & 63) * LC;
    float* bub = bu + r0 * DS;
    unsigned short* xp = xs + r0 * DS;

    float b0v = bub[lane];
    float b1v = bub[DS + lane];
    bbuf[w][0][lane] = b0v;
    asm volatile("" ::: "memory");

    for (int i = 0; i < 32; ++i) {
        // prefetch next b pair (last iter reads past chunk; value unused)
        float nb0 = bub[(2 * i + 2) * DS + lane];
        float nb1 = bub[(2 * i + 3) * DS + lane];
        xbuf[w][lane] = x;
        asm volatile("" ::: "memory");
        float* bb = &bbuf[w][i & 1][0];
        // bdot = A . b_{2i}  (+ b_{2i+1})
        float bp[4];
#pragma unroll
        for (int g = 0; g < 4; ++g) {
            float acc = 0.f;
#pragma unroll
            for (int q = 0; q < 4; ++q) {
                float4 bm = *reinterpret_cast<float4*>(&bb[g * 16 + q * 4]);
                acc = fmaf(a_row[g * 16 + q * 4 + 0], bm.x, acc);
                acc = fmaf(a_row[g * 16 + q * 4 + 1], bm.y, acc);
                acc = fmaf(a_row[g * 16 + q * 4 + 2], bm.z, acc);
                acc = fmaf(a_row[g * 16 + q * 4 + 3], bm.w, acc);
            }
            bp[g] = acc;
        }
        float bdot = ((bp[0] + bp[1]) + (bp[2] + bp[3])) + b1v;
        // xdot = A2 . x_{2i}; pass1 also xo = A . x_{2i} + b_{2i}
        float p2[4], p1d[4];
#pragma unroll
        for (int g = 0; g < 4; ++g) {
            float acc2 = 0.f, acc1 = 0.f;
#pragma unroll
            for (int q = 0; q < 4; ++q) {
                float4 xm = *reinterpret_cast<float4*>(&xbuf[w][g * 16 + q * 4]);
                float c20 = a2_row[g * 16 + q * 4 + 0], c21 = a2_row[g * 16 + q * 4 + 1];
                float c22 = a2_row[g * 16 + q * 4 + 2], c23 = a2_row[g * 16 + q * 4 + 3];
                acc2 = fmaf(c20, xm.x, acc2);
                acc2 = fmaf(c21, xm.y, acc2);
                acc2 = fmaf(c22, xm.z, acc2);
                acc2 = fmaf(c23, xm.w, acc2);
                if (PASS == 1) {
                    float c10 = a_row[g * 16 + q * 4 + 0], c11 = a_row[g * 16 + q * 4 + 1];
                    float c12 = a_row[g * 16 + q * 4 + 2], c13 = a_row[g * 16 + q * 4 + 3];
                    acc1 = fmaf(c10, xm.x, acc1);
                    acc1 = fmaf(c11, xm.y, acc1);
                    acc1 = fmaf(c12, xm.z, acc1);
                    acc1 = fmaf(c13, xm.w, acc1);
                }
            }
            p2[g] = acc2; p1d[g] = acc1;
        }
        float xe = ((p2[0] + p2[1]) + (p2[2] + p2[3])) + bdot;
        if (PASS == 1) {
            float xo = ((p1d[0] + p1d[1]) + (p1d[2] + p1d[3])) + b0v;
            xp[(2 * i) * DS + lane] = bf16_rne(xo);
            xp[(2 * i + 1) * DS + lane] = bf16_rne(xe);
        }
        asm volatile("" ::: "memory");
        bbuf[w][(i + 1) & 1][lane] = nb0;    // broadcast b for next iter
        b0v = nb0; b1v = nb1; x = xe;
    }
    if (PASS == 0) ws[WS_E + (size_t)task * DS + lane] = x;
}

// ---------------- sequential chunk-boundary propagation ----------------
__global__ __launch_bounds__(64) void k_combine(float* __restrict__ ws) {
    const float* Apow = ws + WS_APOW;
    int b = blockIdx.x;
    int lane = threadIdx.x;
    __shared__ float xbuf[64];
    __shared__ float e_lds[NCH][64];         // 16 KB: all E for this batch
    const float* Eb = ws + WS_E + (size_t)b * NCH * DS;
#pragma unroll
    for (int r = 0; r < 16; ++r) {
        int idx = r * 64 + lane;
        int jj = idx >> 4, c4 = (idx & 15) << 2;
        *reinterpret_cast<float4*>(&e_lds[jj][c4]) =
            *reinterpret_cast<const float4*>(&Eb[jj * DS + c4]);
    }
    float p_row[64];
#pragma unroll
    for (int mg = 0; mg < 16; ++mg) {
        float4 v = *reinterpret_cast<const float4*>(&Apow[lane * 64 + mg * 4]);
        p_row[mg * 4 + 0] = v.x; p_row[mg * 4 + 1] = v.y;
        p_row[mg * 4 + 2] = v.z; p_row[mg * 4 + 3] = v.w;
    }
    __syncthreads();
    float x = 0.f;
    for (int jj = 0; jj < NCH; ++jj) {
        size_t task = (size_t)b * NCH + jj;
        ws[WS_S + task * DS + lane] = x;
        float e = e_lds[jj][lane];
        xbuf[lane] = x;
        asm volatile("" ::: "memory");
        float part[4];
#pragma unroll
        for (int g = 0; g < 4; ++g) {
            float acc = (g == 0) ? e : 0.f;
#pragma unroll
            for (int q = 0; q < 4; ++q) {
                float4 xm = *reinterpret_cast<float4*>(&xbuf[g * 16 + q * 4]);
                acc = fmaf(p_row[g * 16 + q * 4 + 0], xm.x, acc);
                acc = fmaf(p_row[g * 16 + q * 4 + 1], xm.y, acc);
                acc = fmaf(p_row[g * 16 + q * 4 + 2], xm.z, acc);
                acc = fmaf(p_row[g * 16 + q * 4 + 3], xm.w, acc);
            }
            part[g] = acc;
        }
        asm volatile("" ::: "memory");
        x = (part[0] + part[1]) + (part[2] + part[3]);
    }
}

// ---------------- GEMM2: y = xs @ C^T + u*D  (M=65536,K=64,N=1024) ----------------
// M-tile 128, N-tile 128, single bf16, 36.8 KB LDS (epilogue reuses tiles in 2 halves).
__global__ __launch_bounds__(256, 4) void k_gemm2(const float* __restrict__ u,
                                                  const float* __restrict__ Dv,
                                                  const float* __restrict__ ws,
                                                  float* __restrict__ y) {
    __shared__ __align__(16) char smem[2 * 128 * 72 * 2];   // 36864 B
    short (*a_t)[72] = (short(*)[72])(smem);
    short (*c_t)[72] = (short(*)[72])(smem + 18432);
    float (*out_lds)[132] = (float(*)[132])(smem);          // 33792 B reused per half

    const unsigned short* xsb = (const unsigned short*)(ws + WS_XS);
    const unsigned short* chig = (const unsigned short*)(ws + WS_CHI);
    int tid = threadIdx.x;
    int m0 = blockIdx.x * 128;
    int d0 = blockIdx.y * 128;
    int wid = tid >> 6, lane = tid & 63;
    int lr = lane & 15, lg = lane >> 4;

#pragma unroll
    for (int rep = 0; rep < 4; ++rep) {            // stage xs tile 128x64 bf16
        int idx = rep * 256 + tid;
        int r = idx >> 3, k8 = (idx & 7) << 3;
        *reinterpret_cast<ushort8*>(&a_t[r][k8]) =
            *reinterpret_cast<const ushort8*>(&xsb[(size_t)(m0 + r) * DS + k8]);
    }
#pragma unroll
    for (int rep = 0; rep < 4; ++rep) {            // stage C tile 128x64 bf16
        int idx = rep * 256 + tid;
        int dl = idx >> 3, n8 = (idx & 7) << 3;
        *reinterpret_cast<ushort8*>(&c_t[dl][n8]) =
            *reinterpret_cast<const ushort8*>(&chig[(size_t)(d0 + dl) * DS + n8]);
    }
    __syncthreads();

    f32x4 acc[2][8];
#pragma unroll
    for (int i = 0; i < 2; ++i)
#pragma unroll
        for (int j = 0; j < 8; ++j) acc[i][j] = (f32x4)(0.f);

#pragma unroll
    for (int kf = 0; kf < 2; ++kf) {
        int kb = kf * 32 + lg * 8;
        bf16x8 ah0 = *reinterpret_cast<bf16x8*>(&a_t[wid * 32 + lr][kb]);
        bf16x8 ah1 = *reinterpret_cast<bf16x8*>(&a_t[wid * 32 + 16 + lr][kb]);
#pragma unroll
        for (int nf = 0; nf < 8; ++nf) {
            bf16x8 cb = *reinterpret_cast<bf16x8*>(&c_t[nf * 16 + lr][kb]);
            acc[0][nf] = __builtin_amdgcn_mfma_f32_16x16x32_bf16(ah0, cb, acc[0][nf], 0, 0, 0);
            acc[1][nf] = __builtin_amdgcn_mfma_f32_16x16x32_bf16(ah1, cb, acc[1][nf], 0, 0, 0);
        }
    }
    __syncthreads();   // all fragment reads done; smem now reusable

#pragma unroll
    for (int h = 0; h < 2; ++h) {
        if ((wid >> 1) == h) {
            int rbase = (wid & 1) * 32;
#pragma unroll
            for (int mf = 0; mf < 2; ++mf)
#pragma unroll
                for (int nf = 0; nf < 8; ++nf)
#pragma unroll
                    for (int q = 0; q < 4; ++q)
                        out_lds[rbase + mf * 16 + lg * 4 + q][nf * 16 + lr] = acc[mf][nf][q];
        }
        __syncthreads();
#pragma unroll
        for (int rep = 0; rep < 8; ++rep) {        // coalesced float4 stores
            int idx = rep * 256 + tid;
            int r = idx >> 5, c4 = (idx & 31) << 2;
            float4 a = *reinterpret_cast<float4*>(&out_lds[r][c4]);
            size_t row = (size_t)(m0 + h * 64 + r);
            int c = d0 + c4;
            float4 uv = *reinterpret_cast<const float4*>(&u[row * DM + c]);
            float4 dv = *reinterpret_cast<const float4*>(&Dv[c]);
            float4 o;
            o.x = a.x + uv.x * dv.x;
            o.y = a.y + uv.y * dv.y;
            o.z = a.z + uv.z * dv.z;
            o.w = a.w + uv.w * dv.w;
            *reinterpret_cast<float4*>(&y[row * DM + c]) = o;
        }
        if (h == 0) __syncthreads();
    }
}

extern "C" void kernel_launch(void* const* d_in, const int* in_sizes, int n_in,
                              void* d_out, int out_size, void* d_ws, size_t ws_size,
                              hipStream_t stream) {
    (void)in_sizes; (void)n_in; (void)out_size; (void)ws_size;
    const float* u      = (const float*)d_in[0];
    const float* A      = (const float*)d_in[1];
    const float* Bm     = (const float*)d_in[2];
    const float* C      = (const float*)d_in[3];
    const float* Dv     = (const float*)d_in[4];
    const float* log_dt = (const float*)d_in[5];
    float* y  = (float*)d_out;
    float* ws = (float*)d_ws;
    float* bu = ws + WS_BU;

    k_prep<<<dim3(1), dim3(256), 0, stream>>>(A, log_dt, ws);
    k_cvt<<<dim3(128), dim3(256), 0, stream>>>(Bm, C, ws);
    // A2 kept for the double-step scan; chain ends with A^64 in WS_APOW.
    k_matsq<<<dim3(16), dim3(256), 0, stream>>>(ws + WS_ABAR, ws + WS_A2);    // A^2
    k_matsq<<<dim3(16), dim3(256), 0, stream>>>(ws + WS_A2,   ws + WS_APOW);  // A^4
    k_matsq<<<dim3(16), dim3(256), 0, stream>>>(ws + WS_APOW, ws + WS_TMP);   // A^8
    k_matsq<<<dim3(16), dim3(256), 0, stream>>>(ws + WS_TMP,  ws + WS_APOW);  // A^16
    k_matsq<<<dim3(16), dim3(256), 0, stream>>>(ws + WS_APOW, ws + WS_TMP);   // A^32
    k_matsq<<<dim3(16), dim3(256), 0, stream>>>(ws + WS_TMP,  ws + WS_APOW);  // A^64

    k_gemm1<<<dim3(MTOT / 64), dim3(256), 0, stream>>>(u, ws, bu);
    k_scan<0><<<dim3(NTASK / 4), dim3(256), 0, stream>>>(ws);
    k_combine<<<dim3(NB), dim3(64), 0, stream>>>(ws);
    k_scan<1><<<dim3(NTASK / 4), dim3(256), 0, stream>>>(ws);
    k_gemm2<<<dim3(MTOT / 128, DM / 128), dim3(256), 0, stream>>>(u, Dv, ws, y);
}

// Round 9
// 329.503 us; speedup vs baseline: 1.1489x; 1.0221x over previous
//
#include <hip/hip_runtime.h>

// S4 layer: y = C * scan(a_bar, dt*B*u) + u*D
//   setup:    dt = mean(exp(log_dt)); A_bar = I + dt*A; B_hat = bf16(dt*B); C_hat = bf16(C)
//   matsq x6: A2 = A_bar^2 (kept for scan); chain continues to A_pow = A_bar^64
//   gemm1:    bu[m][n] = sum_k u[m][k]*(dt*B)[n][k]   (MFMA bf16; A-operand direct
//             global->reg->cvt, B in double-buffered LDS, 1 barrier/K-tile)
//   scan<0>:  per-chunk DOUBLE-STEP scan from zero -> chunk end states E (1 task/wave)
//   combine:  S_{j+1} = A_pow * S_j + E_j
//   scan<1>:  re-run recurrence (double-step, odd states via A-dot); writes xs as bf16
//   gemm2:    y[m][d] = sum_n xs[m][n]*C[d][n] + u[m][d]*D[d]  (MFMA bf16, 128x128 tile)

#define DM   1024
#define DS   64
#define NB   16
#define LL   4096
#define LC   64
#define NCH  (LL / LC)     // 64
#define MTOT (NB * LL)     // 65536
#define NTASK (NB * NCH)   // 1024

// workspace layout in floats
#define WS_ABAR 64
#define WS_A2   4160
#define WS_APOW 8256
#define WS_TMP  12352
#define WS_E    16448
#define WS_S    (WS_E + NTASK * DS)       // 81984
#define WS_BHI  (WS_S + NTASK * DS)       // 147520
#define WS_CHI  (WS_BHI + 32768)          // 180288
#define WS_XS   (WS_CHI + 32768)          // 213056
#define WS_BU   (WS_XS + 2097152)         // 2310208
// total = 2310208 + 4194304 floats ~= 26 MB (ws allocation ~1 GiB per harness fill)

typedef __attribute__((ext_vector_type(4))) float f32x4;
typedef __attribute__((ext_vector_type(8))) short bf16x8;
typedef __attribute__((ext_vector_type(8))) unsigned short ushort8;

__device__ inline unsigned short bf16_rne(float f) {
    unsigned u = __builtin_bit_cast(unsigned, f);
    u += 0x7FFFu + ((u >> 16) & 1u);
    return (unsigned short)(u >> 16);
}

// ---------------- setup: dt + A_bar + B_hat + C_hat in one launch ----------------
// blocks 0..63: B_hat = bf16(dt*B); 64..127: C_hat = bf16(C); 128: A_bar + ws[0].
// Every block recomputes dt with the identical reduction order (bit-stable).
__global__ __launch_bounds__(256) void k_setup(const float* __restrict__ A,
                                               const float* __restrict__ Bm,
                                               const float* __restrict__ C,
                                               const float* __restrict__ log_dt,
                                               float* __restrict__ ws) {
    __shared__ float red[256];
    int tid = threadIdx.x;
    int bid = blockIdx.x;
    float s = 0.f;
    for (int i = tid; i < DM; i += 256) s += expf(log_dt[i]);
    red[tid] = s;
    __syncthreads();
    for (int off = 128; off > 0; off >>= 1) {
        if (tid < off) red[tid] += red[tid + off];
        __syncthreads();
    }
    float dt = red[0] * (1.f / (float)DM);

    if (bid < 128) {
        int isC = bid >> 6;
        const float* src = isC ? C : Bm;
        unsigned short* dst = (unsigned short*)(ws + (isC ? WS_CHI : WS_BHI));
        float scale = isC ? 1.f : dt;
        int i = ((bid & 63) * 256 + tid) * 4;
        float4 v = *reinterpret_cast<const float4*>(&src[i]);
        ushort4 h;
        h.x = bf16_rne(v.x * scale);
        h.y = bf16_rne(v.y * scale);
        h.z = bf16_rne(v.z * scale);
        h.w = bf16_rne(v.w * scale);
        *reinterpret_cast<ushort4*>(&dst[i]) = h;
    } else {
        if (tid == 0) ws[0] = dt;
        for (int idx = tid; idx < 4096; idx += 256) {
            int n = idx >> 6, m = idx & 63;
            ws[WS_ABAR + idx] = dt * A[idx] + ((n == m) ? 1.f : 0.f);
        }
    }
}

// dst = src*src for a 64x64 matrix. grid=16 blocks x 256 thr.
__global__ __launch_bounds__(256) void k_matsq(const float* __restrict__ src,
                                               float* __restrict__ dst) {
    __shared__ float s[64][65];
    int tid = threadIdx.x;
#pragma unroll
    for (int rep = 0; rep < 16; ++rep) {
        int idx = rep * 256 + tid;
        s[idx >> 6][idx & 63] = src[idx];
    }
    __syncthreads();
    int n = (blockIdx.x << 2) + (tid >> 6);  // wave-uniform row
    int m = tid & 63;
    float a0 = 0.f, a1 = 0.f, a2 = 0.f, a3 = 0.f;
#pragma unroll
    for (int k = 0; k < 64; k += 4) {
        a0 = fmaf(s[n][k + 0], s[k + 0][m], a0);
        a1 = fmaf(s[n][k + 1], s[k + 1][m], a1);
        a2 = fmaf(s[n][k + 2], s[k + 2][m], a2);
        a3 = fmaf(s[n][k + 3], s[k + 3][m], a3);
    }
    dst[(n << 6) + m] = (a0 + a1) + (a2 + a3);
}

// ---------------- GEMM1: bu = u @ (dt*B)^T  (M=65536,K=1024,N=64) ----------------
// M-tile 64 (grid 1024 = 4 blocks/CU). A-operand (u rows) is wave-private ->
// direct global->reg->bf16 conversion, no LDS. B in LDS, double-buffered,
// ONE barrier per K-tile. Register prefetch of the next tile during MFMA.
__global__ __launch_bounds__(256, 4) void k_gemm1(const float* __restrict__ u,
                                                  const float* __restrict__ ws,
                                                  float* __restrict__ bu) {
    __shared__ short b_t[2][64][72];   // 18432 B
    const unsigned short* bhig = (const unsigned short*)(ws + WS_BHI);
    int tid = threadIdx.x;
    int m0 = blockIdx.x * 64;
    int wid = tid >> 6, lane = tid & 63;
    int lr = lane & 15, lg = lane >> 4;
    int bn = tid >> 3, bk8 = (tid & 7) << 3;     // B stage: rows bn+32j, col bk8

    // this thread's private A row and k-base (frag: row=wid*16+lr, k=kf*32+lg*8)
    const float* urow = u + (size_t)(m0 + wid * 16 + lr) * DM + lg * 8;

    f32x4 acc[4];
#pragma unroll
    for (int j = 0; j < 4; ++j) acc[j] = (f32x4)(0.f);

    float4 ua[2][2];                 // next-tile raw u frags [kf][half]
    ushort8 rb[2];                   // next-tile B rows
    // preload K-tile 0
#pragma unroll
    for (int kf = 0; kf < 2; ++kf) {
        ua[kf][0] = *reinterpret_cast<const float4*>(&urow[kf * 32]);
        ua[kf][1] = *reinterpret_cast<const float4*>(&urow[kf * 32 + 4]);
    }
#pragma unroll
    for (int j = 0; j < 2; ++j)
        rb[j] = *reinterpret_cast<const ushort8*>(&bhig[(size_t)(bn + 32 * j) * DM + bk8]);

    for (int kt = 0; kt < 16; ++kt) {
        int cur = kt & 1;
        // write staged B to LDS buffer cur
#pragma unroll
        for (int j = 0; j < 2; ++j)
            *reinterpret_cast<ushort8*>(&b_t[cur][bn + 32 * j][bk8]) = rb[j];
        // convert current u frags to bf16
        bf16x8 af[2];
#pragma unroll
        for (int kf = 0; kf < 2; ++kf) {
            ushort8 h;
            h[0] = bf16_rne(ua[kf][0].x); h[1] = bf16_rne(ua[kf][0].y);
            h[2] = bf16_rne(ua[kf][0].z); h[3] = bf16_rne(ua[kf][0].w);
            h[4] = bf16_rne(ua[kf][1].x); h[5] = bf16_rne(ua[kf][1].y);
            h[6] = bf16_rne(ua[kf][1].z); h[7] = bf16_rne(ua[kf][1].w);
            af[kf] = __builtin_bit_cast(bf16x8, h);
        }
        // issue next tile's loads (land during MFMA)
        if (kt + 1 < 16) {
            int k0n = (kt + 1) * 64;
#pragma unroll
            for (int kf = 0; kf < 2; ++kf) {
                ua[kf][0] = *reinterpret_cast<const float4*>(&urow[k0n + kf * 32]);
                ua[kf][1] = *reinterpret_cast<const float4*>(&urow[k0n + kf * 32 + 4]);
            }
#pragma unroll
            for (int j = 0; j < 2; ++j)
                rb[j] = *reinterpret_cast<const ushort8*>(&bhig[(size_t)(bn + 32 * j) * DM + k0n + bk8]);
        }
        __syncthreads();             // B writes to buf[cur] visible
#pragma unroll
        for (int kf = 0; kf < 2; ++kf) {
            int kb = kf * 32 + lg * 8;
#pragma unroll
            for (int nf = 0; nf < 4; ++nf) {
                bf16x8 bf_ = *reinterpret_cast<bf16x8*>(&b_t[cur][nf * 16 + lr][kb]);
                acc[nf] = __builtin_amdgcn_mfma_f32_16x16x32_bf16(af[kf], bf_, acc[nf], 0, 0, 0);
            }
        }
        // no second barrier: next iter writes the OTHER buffer; re-writing this
        // buffer happens 2 iterations (2 barriers) later.
    }
#pragma unroll
    for (int nf = 0; nf < 4; ++nf)
#pragma unroll
        for (int q = 0; q < 4; ++q) {
            size_t row = (size_t)(m0 + wid * 16 + lg * 4 + q);
            bu[row * DS + nf * 16 + lr] = acc[nf][q];
        }
}

// ---------------- chunked scan, DOUBLE-STEP: 1 task per wave, 1024 waves ----------------
// x_{2i+1} = A x_{2i} + b_{2i}            (pass1 only)
// x_{2i+2} = A2 x_{2i} + (A b_{2i} + b_{2i+1})
// b-broadcast double-buffered in LDS, written one iteration ahead.
// Prefetches read up to 512 B past the chunk (in-bounds of ~1 GiB ws).
template <int PASS>
__global__ __launch_bounds__(256) void k_scan(float* __restrict__ ws) {
    const float* Abar = ws + WS_ABAR;
    const float* A2m  = ws + WS_A2;
    float* bu = ws + WS_BU;
    unsigned short* xs = (unsigned short*)(ws + WS_XS);
    int tid = threadIdx.x;
    int w = tid >> 6, lane = tid & 63;
    int task = blockIdx.x * 4 + w;          // 0..1023
    __shared__ float xbuf[4][64];
    __shared__ float bbuf[4][2][64];

    float a_row[64], a2_row[64];
#pragma unroll
    for (int mg = 0; mg < 16; ++mg) {
        float4 v = *reinterpret_cast<const float4*>(&Abar[lane * 64 + mg * 4]);
        a_row[mg * 4 + 0] = v.x; a_row[mg * 4 + 1] = v.y;
        a_row[mg * 4 + 2] = v.z; a_row[mg * 4 + 3] = v.w;
        float4 v2 = *reinterpret_cast<const float4*>(&A2m[lane * 64 + mg * 4]);
        a2_row[mg * 4 + 0] = v2.x; a2_row[mg * 4 + 1] = v2.y;
        a2_row[mg * 4 + 2] = v2.z; a2_row[mg * 4 + 3] = v2.w;
    }
    float x;
    if (PASS == 0) x = 0.f;
    else           x = ws[WS_S + (size_t)task * DS + lane];

    size_t r0 = (size_t)(task >> 6) * LL + (size_t)(task & 63) * LC;
    float* bub = bu + r0 * DS;
    unsigned short* xp = xs + r0 * DS;

    float b0v = bub[lane];
    float b1v = bub[DS + lane];
    bbuf[w][0][lane] = b0v;
    asm volatile("" ::: "memory");

    for (int i = 0; i < 32; ++i) {
        // prefetch next b pair (last iter reads past chunk; value unused)
        float nb0 = bub[(2 * i + 2) * DS + lane];
        float nb1 = bub[(2 * i + 3) * DS + lane];
        xbuf[w][lane] = x;
        asm volatile("" ::: "memory");
        float* bb = &bbuf[w][i & 1][0];
        // bdot = A . b_{2i}  (+ b_{2i+1})
        float bp[4];
#pragma unroll
        for (int g = 0; g < 4; ++g) {
            float acc = 0.f;
#pragma unroll
            for (int q = 0; q < 4; ++q) {
                float4 bm = *reinterpret_cast<float4*>(&bb[g * 16 + q * 4]);
                acc = fmaf(a_row[g * 16 + q * 4 + 0], bm.x, acc);
                acc = fmaf(a_row[g * 16 + q * 4 + 1], bm.y, acc);
                acc = fmaf(a_row[g * 16 + q * 4 + 2], bm.z, acc);
                acc = fmaf(a_row[g * 16 + q * 4 + 3], bm.w, acc);
            }
            bp[g] = acc;
        }
        float bdot = ((bp[0] + bp[1]) + (bp[2] + bp[3])) + b1v;
        // xdot = A2 . x_{2i}; pass1 also xo = A . x_{2i} + b_{2i}
        float p2[4], p1d[4];
#pragma unroll
        for (int g = 0; g < 4; ++g) {
            float acc2 = 0.f, acc1 = 0.f;
#pragma unroll
            for (int q = 0; q < 4; ++q) {
                float4 xm = *reinterpret_cast<float4*>(&xbuf[w][g * 16 + q * 4]);
                float c20 = a2_row[g * 16 + q * 4 + 0], c21 = a2_row[g * 16 + q * 4 + 1];
                float c22 = a2_row[g * 16 + q * 4 + 2], c23 = a2_row[g * 16 + q * 4 + 3];
                acc2 = fmaf(c20, xm.x, acc2);
                acc2 = fmaf(c21, xm.y, acc2);
                acc2 = fmaf(c22, xm.z, acc2);
                acc2 = fmaf(c23, xm.w, acc2);
                if (PASS == 1) {
                    float c10 = a_row[g * 16 + q * 4 + 0], c11 = a_row[g * 16 + q * 4 + 1];
                    float c12 = a_row[g * 16 + q * 4 + 2], c13 = a_row[g * 16 + q * 4 + 3];
                    acc1 = fmaf(c10, xm.x, acc1);
                    acc1 = fmaf(c11, xm.y, acc1);
                    acc1 = fmaf(c12, xm.z, acc1);
                    acc1 = fmaf(c13, xm.w, acc1);
                }
            }
            p2[g] = acc2; p1d[g] = acc1;
        }
        float xe = ((p2[0] + p2[1]) + (p2[2] + p2[3])) + bdot;
        if (PASS == 1) {
            float xo = ((p1d[0] + p1d[1]) + (p1d[2] + p1d[3])) + b0v;
            xp[(2 * i) * DS + lane] = bf16_rne(xo);
            xp[(2 * i + 1) * DS + lane] = bf16_rne(xe);
        }
        asm volatile("" ::: "memory");
        bbuf[w][(i + 1) & 1][lane] = nb0;    // broadcast b for next iter
        b0v = nb0; b1v = nb1; x = xe;
    }
    if (PASS == 0) ws[WS_E + (size_t)task * DS + lane] = x;
}

// ---------------- sequential chunk-boundary propagation ----------------
__global__ __launch_bounds__(64) void k_combine(float* __restrict__ ws) {
    const float* Apow = ws + WS_APOW;
    int b = blockIdx.x;
    int lane = threadIdx.x;
    __shared__ float xbuf[64];
    __shared__ float e_lds[NCH][64];         // 16 KB: all E for this batch
    const float* Eb = ws + WS_E + (size_t)b * NCH * DS;
#pragma unroll
    for (int r = 0; r < 16; ++r) {
        int idx = r * 64 + lane;
        int jj = idx >> 4, c4 = (idx & 15) << 2;
        *reinterpret_cast<float4*>(&e_lds[jj][c4]) =
            *reinterpret_cast<const float4*>(&Eb[jj * DS + c4]);
    }
    float p_row[64];
#pragma unroll
    for (int mg = 0; mg < 16; ++mg) {
        float4 v = *reinterpret_cast<const float4*>(&Apow[lane * 64 + mg * 4]);
        p_row[mg * 4 + 0] = v.x; p_row[mg * 4 + 1] = v.y;
        p_row[mg * 4 + 2] = v.z; p_row[mg * 4 + 3] = v.w;
    }
    __syncthreads();
    float x = 0.f;
    for (int jj = 0; jj < NCH; ++jj) {
        size_t task = (size_t)b * NCH + jj;
        ws[WS_S + task * DS + lane] = x;
        float e = e_lds[jj][lane];
        xbuf[lane] = x;
        asm volatile("" ::: "memory");
        float part[4];
#pragma unroll
        for (int g = 0; g < 4; ++g) {
            float acc = (g == 0) ? e : 0.f;
#pragma unroll
            for (int q = 0; q < 4; ++q) {
                float4 xm = *reinterpret_cast<float4*>(&xbuf[g * 16 + q * 4]);
                acc = fmaf(p_row[g * 16 + q * 4 + 0], xm.x, acc);
                acc = fmaf(p_row[g * 16 + q * 4 + 1], xm.y, acc);
                acc = fmaf(p_row[g * 16 + q * 4 + 2], xm.z, acc);
                acc = fmaf(p_row[g * 16 + q * 4 + 3], xm.w, acc);
            }
            part[g] = acc;
        }
        asm volatile("" ::: "memory");
        x = (part[0] + part[1]) + (part[2] + part[3]);
    }
}

// ---------------- GEMM2: y = xs @ C^T + u*D  (M=65536,K=64,N=1024) ----------------
// M-tile 128, N-tile 128, single bf16, 36.8 KB LDS (epilogue reuses tiles in 2 halves).
__global__ __launch_bounds__(256, 4) void k_gemm2(const float* __restrict__ u,
                                                  const float* __restrict__ Dv,
                                                  const float* __restrict__ ws,
                                                  float* __restrict__ y) {
    __shared__ __align__(16) char smem[2 * 128 * 72 * 2];   // 36864 B
    short (*a_t)[72] = (short(*)[72])(smem);
    short (*c_t)[72] = (short(*)[72])(smem + 18432);
    float (*out_lds)[132] = (float(*)[132])(smem);          // 33792 B reused per half

    const unsigned short* xsb = (const unsigned short*)(ws + WS_XS);
    const unsigned short* chig = (const unsigned short*)(ws + WS_CHI);
    int tid = threadIdx.x;
    int m0 = blockIdx.x * 128;
    int d0 = blockIdx.y * 128;
    int wid = tid >> 6, lane = tid & 63;
    int lr = lane & 15, lg = lane >> 4;

#pragma unroll
    for (int rep = 0; rep < 4; ++rep) {            // stage xs tile 128x64 bf16
        int idx = rep * 256 + tid;
        int r = idx >> 3, k8 = (idx & 7) << 3;
        *reinterpret_cast<ushort8*>(&a_t[r][k8]) =
            *reinterpret_cast<const ushort8*>(&xsb[(size_t)(m0 + r) * DS + k8]);
    }
#pragma unroll
    for (int rep = 0; rep < 4; ++rep) {            // stage C tile 128x64 bf16
        int idx = rep * 256 + tid;
        int dl = idx >> 3, n8 = (idx & 7) << 3;
        *reinterpret_cast<ushort8*>(&c_t[dl][n8]) =
            *reinterpret_cast<const ushort8*>(&chig[(size_t)(d0 + dl) * DS + n8]);
    }
    __syncthreads();

    f32x4 acc[2][8];
#pragma unroll
    for (int i = 0; i < 2; ++i)
#pragma unroll
        for (int j = 0; j < 8; ++j) acc[i][j] = (f32x4)(0.f);

#pragma unroll
    for (int kf = 0; kf < 2; ++kf) {
        int kb = kf * 32 + lg * 8;
        bf16x8 ah0 = *reinterpret_cast<bf16x8*>(&a_t[wid * 32 + lr][kb]);
        bf16x8 ah1 = *reinterpret_cast<bf16x8*>(&a_t[wid * 32 + 16 + lr][kb]);
#pragma unroll
        for (int nf = 0; nf < 8; ++nf) {
            bf16x8 cb = *reinterpret_cast<bf16x8*>(&c_t[nf * 16 + lr][kb]);
            acc[0][nf] = __builtin_amdgcn_mfma_f32_16x16x32_bf16(ah0, cb, acc[0][nf], 0, 0, 0);
            acc[1][nf] = __builtin_amdgcn_mfma_f32_16x16x32_bf16(ah1, cb, acc[1][nf], 0, 0, 0);
        }
    }
    __syncthreads();   // all fragment reads done; smem now reusable

#pragma unroll
    for (int h = 0; h < 2; ++h) {
        if ((wid >> 1) == h) {
            int rbase = (wid & 1) * 32;
#pragma unroll
            for (int mf = 0; mf < 2; ++mf)
#pragma unroll
                for (int nf = 0; nf < 8; ++nf)
#pragma unroll
                    for (int q = 0; q < 4; ++q)
                        out_lds[rbase + mf * 16 + lg * 4 + q][nf * 16 + lr] = acc[mf][nf][q];
        }
        __syncthreads();
#pragma unroll
        for (int rep = 0; rep < 8; ++rep) {        // coalesced float4 stores
            int idx = rep * 256 + tid;
            int r = idx >> 5, c4 = (idx & 31) << 2;
            float4 a = *reinterpret_cast<float4*>(&out_lds[r][c4]);
            size_t row = (size_t)(m0 + h * 64 + r);
            int c = d0 + c4;
            float4 uv = *reinterpret_cast<const float4*>(&u[row * DM + c]);
            float4 dv = *reinterpret_cast<const float4*>(&Dv[c]);
            float4 o;
            o.x = a.x + uv.x * dv.x;
            o.y = a.y + uv.y * dv.y;
            o.z = a.z + uv.z * dv.z;
            o.w = a.w + uv.w * dv.w;
            *reinterpret_cast<float4*>(&y[row * DM + c]) = o;
        }
        if (h == 0) __syncthreads();
    }
}

extern "C" void kernel_launch(void* const* d_in, const int* in_sizes, int n_in,
                              void* d_out, int out_size, void* d_ws, size_t ws_size,
                              hipStream_t stream) {
    (void)in_sizes; (void)n_in; (void)out_size; (void)ws_size;
    const float* u      = (const float*)d_in[0];
    const float* A      = (const float*)d_in[1];
    const float* Bm     = (const float*)d_in[2];
    const float* C      = (const float*)d_in[3];
    const float* Dv     = (const float*)d_in[4];
    const float* log_dt = (const float*)d_in[5];
    float* y  = (float*)d_out;
    float* ws = (float*)d_ws;
    float* bu = ws + WS_BU;

    k_setup<<<dim3(129), dim3(256), 0, stream>>>(A, Bm, C, log_dt, ws);
    // A2 kept for the double-step scan; chain ends with A^64 in WS_APOW.
    k_matsq<<<dim3(16), dim3(256), 0, stream>>>(ws + WS_ABAR, ws + WS_A2);    // A^2
    k_matsq<<<dim3(16), dim3(256), 0, stream>>>(ws + WS_A2,   ws + WS_APOW);  // A^4
    k_matsq<<<dim3(16), dim3(256), 0, stream>>>(ws + WS_APOW, ws + WS_TMP);   // A^8
    k_matsq<<<dim3(16), dim3(256), 0, stream>>>(ws + WS_TMP,  ws + WS_APOW);  // A^16
    k_matsq<<<dim3(16), dim3(256), 0, stream>>>(ws + WS_APOW, ws + WS_TMP);   // A^32
    k_matsq<<<dim3(16), dim3(256), 0, stream>>>(ws + WS_TMP,  ws + WS_APOW);  // A^64

    k_gemm1<<<dim3(MTOT / 64), dim3(256), 0, stream>>>(u, ws, bu);
    k_scan<0><<<dim3(NTASK / 4), dim3(256), 0, stream>>>(ws);
    k_combine<<<dim3(NB), dim3(64), 0, stream>>>(ws);
    k_scan<1><<<dim3(NTASK / 4), dim3(256), 0, stream>>>(ws);
    k_gemm2<<<dim3(MTOT / 128, DM / 128), dim3(256), 0, stream>>>(u, Dv, ws, y);
}

// Round 10
// 322.608 us; speedup vs baseline: 1.1734x; 1.0214x over previous
//
#include <hip/hip_runtime.h>

// S4 layer: y = C * scan(a_bar, dt*B*u) + u*D
//   setup:    dt = mean(exp(log_dt)); A_bar = I + dt*A; B_hat = bf16(dt*B); C_hat = bf16(C)
//   matsq x6: A2 = A_bar^2 (kept for scan); chain continues to A_pow = A_bar^64
//   gemm1:    bu[m][n] = sum_k u[m][k]*(dt*B)[n][k]   (MFMA bf16; A-operand direct
//             global->reg->cvt via NT loads, B in double-buffered LDS, 1 barrier/K-tile)
//   scan<0>:  per-chunk DOUBLE-STEP scan from zero -> chunk end states E (1 task/wave)
//   combine:  S_{j+1} = A_pow * S_j + E_j
//   scan<1>:  re-run recurrence (double-step, odd states via A-dot); writes xs as bf16
//   gemm2:    y[m][d] = sum_n xs[m][n]*C[d][n] + u[m][d]*D[d]  (MFMA bf16; NT u loads,
//             NT y stores — single-use streams bypass cache, reuse set stays resident)

#define DM   1024
#define DS   64
#define NB   16
#define LL   4096
#define LC   64
#define NCH  (LL / LC)     // 64
#define MTOT (NB * LL)     // 65536
#define NTASK (NB * NCH)   // 1024

// workspace layout in floats
#define WS_ABAR 64
#define WS_A2   4160
#define WS_APOW 8256
#define WS_TMP  12352
#define WS_E    16448
#define WS_S    (WS_E + NTASK * DS)       // 81984
#define WS_BHI  (WS_S + NTASK * DS)       // 147520
#define WS_CHI  (WS_BHI + 32768)          // 180288
#define WS_XS   (WS_CHI + 32768)          // 213056
#define WS_BU   (WS_XS + 2097152)         // 2310208
// total = 2310208 + 4194304 floats ~= 26 MB (ws allocation ~1 GiB per harness fill)

typedef __attribute__((ext_vector_type(4))) float f32x4;
typedef __attribute__((ext_vector_type(8))) short bf16x8;
typedef __attribute__((ext_vector_type(8))) unsigned short ushort8;

__device__ inline unsigned short bf16_rne(float f) {
    unsigned u = __builtin_bit_cast(unsigned, f);
    u += 0x7FFFu + ((u >> 16) & 1u);
    return (unsigned short)(u >> 16);
}
__device__ inline f32x4 nt_load4(const float* p) {
    return __builtin_nontemporal_load(reinterpret_cast<const f32x4*>(p));
}
__device__ inline void nt_store4(float* p, f32x4 v) {
    __builtin_nontemporal_store(v, reinterpret_cast<f32x4*>(p));
}

// ---------------- setup: dt + A_bar + B_hat + C_hat in one launch ----------------
// blocks 0..63: B_hat = bf16(dt*B); 64..127: C_hat = bf16(C); 128: A_bar + ws[0].
// Every block recomputes dt with the identical reduction order (bit-stable).
__global__ __launch_bounds__(256) void k_setup(const float* __restrict__ A,
                                               const float* __restrict__ Bm,
                                               const float* __restrict__ C,
                                               const float* __restrict__ log_dt,
                                               float* __restrict__ ws) {
    __shared__ float red[256];
    int tid = threadIdx.x;
    int bid = blockIdx.x;
    float s = 0.f;
    for (int i = tid; i < DM; i += 256) s += expf(log_dt[i]);
    red[tid] = s;
    __syncthreads();
    for (int off = 128; off > 0; off >>= 1) {
        if (tid < off) red[tid] += red[tid + off];
        __syncthreads();
    }
    float dt = red[0] * (1.f / (float)DM);

    if (bid < 128) {
        int isC = bid >> 6;
        const float* src = isC ? C : Bm;
        unsigned short* dst = (unsigned short*)(ws + (isC ? WS_CHI : WS_BHI));
        float scale = isC ? 1.f : dt;
        int i = ((bid & 63) * 256 + tid) * 4;
        float4 v = *reinterpret_cast<const float4*>(&src[i]);
        ushort4 h;
        h.x = bf16_rne(v.x * scale);
        h.y = bf16_rne(v.y * scale);
        h.z = bf16_rne(v.z * scale);
        h.w = bf16_rne(v.w * scale);
        *reinterpret_cast<ushort4*>(&dst[i]) = h;
    } else {
        if (tid == 0) ws[0] = dt;
        for (int idx = tid; idx < 4096; idx += 256) {
            int n = idx >> 6, m = idx & 63;
            ws[WS_ABAR + idx] = dt * A[idx] + ((n == m) ? 1.f : 0.f);
        }
    }
}

// dst = src*src for a 64x64 matrix. grid=16 blocks x 256 thr.
__global__ __launch_bounds__(256) void k_matsq(const float* __restrict__ src,
                                               float* __restrict__ dst) {
    __shared__ float s[64][65];
    int tid = threadIdx.x;
#pragma unroll
    for (int rep = 0; rep < 16; ++rep) {
        int idx = rep * 256 + tid;
        s[idx >> 6][idx & 63] = src[idx];
    }
    __syncthreads();
    int n = (blockIdx.x << 2) + (tid >> 6);  // wave-uniform row
    int m = tid & 63;
    float a0 = 0.f, a1 = 0.f, a2 = 0.f, a3 = 0.f;
#pragma unroll
    for (int k = 0; k < 64; k += 4) {
        a0 = fmaf(s[n][k + 0], s[k + 0][m], a0);
        a1 = fmaf(s[n][k + 1], s[k + 1][m], a1);
        a2 = fmaf(s[n][k + 2], s[k + 2][m], a2);
        a3 = fmaf(s[n][k + 3], s[k + 3][m], a3);
    }
    dst[(n << 6) + m] = (a0 + a1) + (a2 + a3);
}

// ---------------- GEMM1: bu = u @ (dt*B)^T  (M=65536,K=1024,N=64) ----------------
// M-tile 64 (grid 1024 = 4 blocks/CU). A-operand (u rows) is wave-private ->
// direct NT global->reg->bf16 conversion, no LDS. B in LDS, double-buffered,
// ONE barrier per K-tile. Register prefetch of the next tile during MFMA.
__global__ __launch_bounds__(256, 4) void k_gemm1(const float* __restrict__ u,
                                                  const float* __restrict__ ws,
                                                  float* __restrict__ bu) {
    __shared__ short b_t[2][64][72];   // 18432 B
    const unsigned short* bhig = (const unsigned short*)(ws + WS_BHI);
    int tid = threadIdx.x;
    int m0 = blockIdx.x * 64;
    int wid = tid >> 6, lane = tid & 63;
    int lr = lane & 15, lg = lane >> 4;
    int bn = tid >> 3, bk8 = (tid & 7) << 3;     // B stage: rows bn+32j, col bk8

    // this thread's private A row and k-base (frag: row=wid*16+lr, k=kf*32+lg*8)
    const float* urow = u + (size_t)(m0 + wid * 16 + lr) * DM + lg * 8;

    f32x4 acc[4];
#pragma unroll
    for (int j = 0; j < 4; ++j) acc[j] = (f32x4)(0.f);

    f32x4 ua[2][2];                  // next-tile raw u frags [kf][half]
    ushort8 rb[2];                   // next-tile B rows
    // preload K-tile 0
#pragma unroll
    for (int kf = 0; kf < 2; ++kf) {
        ua[kf][0] = nt_load4(&urow[kf * 32]);
        ua[kf][1] = nt_load4(&urow[kf * 32 + 4]);
    }
#pragma unroll
    for (int j = 0; j < 2; ++j)
        rb[j] = *reinterpret_cast<const ushort8*>(&bhig[(size_t)(bn + 32 * j) * DM + bk8]);

    for (int kt = 0; kt < 16; ++kt) {
        int cur = kt & 1;
        // write staged B to LDS buffer cur
#pragma unroll
        for (int j = 0; j < 2; ++j)
            *reinterpret_cast<ushort8*>(&b_t[cur][bn + 32 * j][bk8]) = rb[j];
        // convert current u frags to bf16
        bf16x8 af[2];
#pragma unroll
        for (int kf = 0; kf < 2; ++kf) {
            ushort8 h;
            h[0] = bf16_rne(ua[kf][0][0]); h[1] = bf16_rne(ua[kf][0][1]);
            h[2] = bf16_rne(ua[kf][0][2]); h[3] = bf16_rne(ua[kf][0][3]);
            h[4] = bf16_rne(ua[kf][1][0]); h[5] = bf16_rne(ua[kf][1][1]);
            h[6] = bf16_rne(ua[kf][1][2]); h[7] = bf16_rne(ua[kf][1][3]);
            af[kf] = __builtin_bit_cast(bf16x8, h);
        }
        // issue next tile's loads (land during MFMA)
        if (kt + 1 < 16) {
            int k0n = (kt + 1) * 64;
#pragma unroll
            for (int kf = 0; kf < 2; ++kf) {
                ua[kf][0] = nt_load4(&urow[k0n + kf * 32]);
                ua[kf][1] = nt_load4(&urow[k0n + kf * 32 + 4]);
            }
#pragma unroll
            for (int j = 0; j < 2; ++j)
                rb[j] = *reinterpret_cast<const ushort8*>(&bhig[(size_t)(bn + 32 * j) * DM + k0n + bk8]);
        }
        __syncthreads();             // B writes to buf[cur] visible
#pragma unroll
        for (int kf = 0; kf < 2; ++kf) {
            int kb = kf * 32 + lg * 8;
#pragma unroll
            for (int nf = 0; nf < 4; ++nf) {
                bf16x8 bf_ = *reinterpret_cast<bf16x8*>(&b_t[cur][nf * 16 + lr][kb]);
                acc[nf] = __builtin_amdgcn_mfma_f32_16x16x32_bf16(af[kf], bf_, acc[nf], 0, 0, 0);
            }
        }
        // no second barrier: next iter writes the OTHER buffer; re-writing this
        // buffer happens 2 iterations (2 barriers) later.
    }
#pragma unroll
    for (int nf = 0; nf < 4; ++nf)
#pragma unroll
        for (int q = 0; q < 4; ++q) {
            size_t row = (size_t)(m0 + wid * 16 + lg * 4 + q);
            bu[row * DS + nf * 16 + lr] = acc[nf][q];   // cached: scans re-read bu
        }
}

// ---------------- chunked scan, DOUBLE-STEP: 1 task per wave, 1024 waves ----------------
// x_{2i+1} = A x_{2i} + b_{2i}            (pass1 only)
// x_{2i+2} = A2 x_{2i} + (A b_{2i} + b_{2i+1})
// b-broadcast double-buffered in LDS, written one iteration ahead.
// Prefetches read up to 512 B past the chunk (in-bounds of ~1 GiB ws).
template <int PASS>
__global__ __launch_bounds__(256) void k_scan(float* __restrict__ ws) {
    const float* Abar = ws + WS_ABAR;
    const float* A2m  = ws + WS_A2;
    float* bu = ws + WS_BU;
    unsigned short* xs = (unsigned short*)(ws + WS_XS);
    int tid = threadIdx.x;
    int w = tid >> 6, lane = tid & 63;
    int task = blockIdx.x * 4 + w;          // 0..1023
    __shared__ float xbuf[4][64];
    __shared__ float bbuf[4][2][64];

    float a_row[64], a2_row[64];
#pragma unroll
    for (int mg = 0; mg < 16; ++mg) {
        float4 v = *reinterpret_cast<const float4*>(&Abar[lane * 64 + mg * 4]);
        a_row[mg * 4 + 0] = v.x; a_row[mg * 4 + 1] = v.y;
        a_row[mg * 4 + 2] = v.z; a_row[mg * 4 + 3] = v.w;
        float4 v2 = *reinterpret_cast<const float4*>(&A2m[lane * 64 + mg * 4]);
        a2_row[mg * 4 + 0] = v2.x; a2_row[mg * 4 + 1] = v2.y;
        a2_row[mg * 4 + 2] = v2.z; a2_row[mg * 4 + 3] = v2.w;
    }
    float x;
    if (PASS == 0) x = 0.f;
    else           x = ws[WS_S + (size_t)task * DS + lane];

    size_t r0 = (size_t)(task >> 6) * LL + (size_t)(task & 63) * LC;
    float* bub = bu + r0 * DS;
    unsigned short* xp = xs + r0 * DS;

    float b0v = bub[lane];
    float b1v = bub[DS + lane];
    bbuf[w][0][lane] = b0v;
    asm volatile("" ::: "memory");

    for (int i = 0; i < 32; ++i) {
        // prefetch next b pair (last iter reads past chunk; value unused)
        float nb0 = bub[(2 * i + 2) * DS + lane];
        float nb1 = bub[(2 * i + 3) * DS + lane];
        xbuf[w][lane] = x;
        asm volatile("" ::: "memory");
        float* bb = &bbuf[w][i & 1][0];
        // bdot = A . b_{2i}  (+ b_{2i+1})
        float bp[4];
#pragma unroll
        for (int g = 0; g < 4; ++g) {
            float acc = 0.f;
#pragma unroll
            for (int q = 0; q < 4; ++q) {
                float4 bm = *reinterpret_cast<float4*>(&bb[g * 16 + q * 4]);
                acc = fmaf(a_row[g * 16 + q * 4 + 0], bm.x, acc);
                acc = fmaf(a_row[g * 16 + q * 4 + 1], bm.y, acc);
                acc = fmaf(a_row[g * 16 + q * 4 + 2], bm.z, acc);
                acc = fmaf(a_row[g * 16 + q * 4 + 3], bm.w, acc);
            }
            bp[g] = acc;
        }
        float bdot = ((bp[0] + bp[1]) + (bp[2] + bp[3])) + b1v;
        // xdot = A2 . x_{2i}; pass1 also xo = A . x_{2i} + b_{2i}
        float p2[4], p1d[4];
#pragma unroll
        for (int g = 0; g < 4; ++g) {
            float acc2 = 0.f, acc1 = 0.f;
#pragma unroll
            for (int q = 0; q < 4; ++q) {
                float4 xm = *reinterpret_cast<float4*>(&xbuf[w][g * 16 + q * 4]);
                float c20 = a2_row[g * 16 + q * 4 + 0], c21 = a2_row[g * 16 + q * 4 + 1];
                float c22 = a2_row[g * 16 + q * 4 + 2], c23 = a2_row[g * 16 + q * 4 + 3];
                acc2 = fmaf(c20, xm.x, acc2);
                acc2 = fmaf(c21, xm.y, acc2);
                acc2 = fmaf(c22, xm.z, acc2);
                acc2 = fmaf(c23, xm.w, acc2);
                if (PASS == 1) {
                    float c10 = a_row[g * 16 + q * 4 + 0], c11 = a_row[g * 16 + q * 4 + 1];
                    float c12 = a_row[g * 16 + q * 4 + 2], c13 = a_row[g * 16 + q * 4 + 3];
                    acc1 = fmaf(c10, xm.x, acc1);
                    acc1 = fmaf(c11, xm.y, acc1);
                    acc1 = fmaf(c12, xm.z, acc1);
                    acc1 = fmaf(c13, xm.w, acc1);
                }
            }
            p2[g] = acc2; p1d[g] = acc1;
        }
        float xe = ((p2[0] + p2[1]) + (p2[2] + p2[3])) + bdot;
        if (PASS == 1) {
            float xo = ((p1d[0] + p1d[1]) + (p1d[2] + p1d[3])) + b0v;
            xp[(2 * i) * DS + lane] = bf16_rne(xo);
            xp[(2 * i + 1) * DS + lane] = bf16_rne(xe);
        }
        asm volatile("" ::: "memory");
        bbuf[w][(i + 1) & 1][lane] = nb0;    // broadcast b for next iter
        b0v = nb0; b1v = nb1; x = xe;
    }
    if (PASS == 0) ws[WS_E + (size_t)task * DS + lane] = x;
}

// ---------------- sequential chunk-boundary propagation ----------------
__global__ __launch_bounds__(64) void k_combine(float* __restrict__ ws) {
    const float* Apow = ws + WS_APOW;
    int b = blockIdx.x;
    int lane = threadIdx.x;
    __shared__ float xbuf[64];
    __shared__ float e_lds[NCH][64];         // 16 KB: all E for this batch
    const float* Eb = ws + WS_E + (size_t)b * NCH * DS;
#pragma unroll
    for (int r = 0; r < 16; ++r) {
        int idx = r * 64 + lane;
        int jj = idx >> 4, c4 = (idx & 15) << 2;
        *reinterpret_cast<float4*>(&e_lds[jj][c4]) =
            *reinterpret_cast<const float4*>(&Eb[jj * DS + c4]);
    }
    float p_row[64];
#pragma unroll
    for (int mg = 0; mg < 16; ++mg) {
        float4 v = *reinterpret_cast<const float4*>(&Apow[lane * 64 + mg * 4]);
        p_row[mg * 4 + 0] = v.x; p_row[mg * 4 + 1] = v.y;
        p_row[mg * 4 + 2] = v.z; p_row[mg * 4 + 3] = v.w;
    }
    __syncthreads();
    float x = 0.f;
    for (int jj = 0; jj < NCH; ++jj) {
        size_t task = (size_t)b * NCH + jj;
        ws[WS_S + task * DS + lane] = x;
        float e = e_lds[jj][lane];
        xbuf[lane] = x;
        asm volatile("" ::: "memory");
        float part[4];
#pragma unroll
        for (int g = 0; g < 4; ++g) {
            float acc = (g == 0) ? e : 0.f;
#pragma unroll
            for (int q = 0; q < 4; ++q) {
                float4 xm = *reinterpret_cast<float4*>(&xbuf[g * 16 + q * 4]);
                acc = fmaf(p_row[g * 16 + q * 4 + 0], xm.x, acc);
                acc = fmaf(p_row[g * 16 + q * 4 + 1], xm.y, acc);
                acc = fmaf(p_row[g * 16 + q * 4 + 2], xm.z, acc);
                acc = fmaf(p_row[g * 16 + q * 4 + 3], xm.w, acc);
            }
            part[g] = acc;
        }
        asm volatile("" ::: "memory");
        x = (part[0] + part[1]) + (part[2] + part[3]);
    }
}

// ---------------- GEMM2: y = xs @ C^T + u*D  (M=65536,K=64,N=1024) ----------------
// M-tile 128, N-tile 128, single bf16, 36.8 KB LDS (epilogue reuses tiles in 2 halves).
// NT loads for u, NT stores for y (single-use); xs/C stay on the cached path.
__global__ __launch_bounds__(256, 4) void k_gemm2(const float* __restrict__ u,
                                                  const float* __restrict__ Dv,
                                                  const float* __restrict__ ws,
                                                  float* __restrict__ y) {
    __shared__ __align__(16) char smem[2 * 128 * 72 * 2];   // 36864 B
    short (*a_t)[72] = (short(*)[72])(smem);
    short (*c_t)[72] = (short(*)[72])(smem + 18432);
    float (*out_lds)[132] = (float(*)[132])(smem);          // 33792 B reused per half

    const unsigned short* xsb = (const unsigned short*)(ws + WS_XS);
    const unsigned short* chig = (const unsigned short*)(ws + WS_CHI);
    int tid = threadIdx.x;
    int m0 = blockIdx.x * 128;
    int d0 = blockIdx.y * 128;
    int wid = tid >> 6, lane = tid & 63;
    int lr = lane & 15, lg = lane >> 4;

#pragma unroll
    for (int rep = 0; rep < 4; ++rep) {            // stage xs tile 128x64 bf16
        int idx = rep * 256 + tid;
        int r = idx >> 3, k8 = (idx & 7) << 3;
        *reinterpret_cast<ushort8*>(&a_t[r][k8]) =
            *reinterpret_cast<const ushort8*>(&xsb[(size_t)(m0 + r) * DS + k8]);
    }
#pragma unroll
    for (int rep = 0; rep < 4; ++rep) {            // stage C tile 128x64 bf16
        int idx = rep * 256 + tid;
        int dl = idx >> 3, n8 = (idx & 7) << 3;
        *reinterpret_cast<ushort8*>(&c_t[dl][n8]) =
            *reinterpret_cast<const ushort8*>(&chig[(size_t)(d0 + dl) * DS + n8]);
    }
    __syncthreads();

    f32x4 acc[2][8];
#pragma unroll
    for (int i = 0; i < 2; ++i)
#pragma unroll
        for (int j = 0; j < 8; ++j) acc[i][j] = (f32x4)(0.f);

#pragma unroll
    for (int kf = 0; kf < 2; ++kf) {
        int kb = kf * 32 + lg * 8;
        bf16x8 ah0 = *reinterpret_cast<bf16x8*>(&a_t[wid * 32 + lr][kb]);
        bf16x8 ah1 = *reinterpret_cast<bf16x8*>(&a_t[wid * 32 + 16 + lr][kb]);
#pragma unroll
        for (int nf = 0; nf < 8; ++nf) {
            bf16x8 cb = *reinterpret_cast<bf16x8*>(&c_t[nf * 16 + lr][kb]);
            acc[0][nf] = __builtin_amdgcn_mfma_f32_16x16x32_bf16(ah0, cb, acc[0][nf], 0, 0, 0);
            acc[1][nf] = __builtin_amdgcn_mfma_f32_16x16x32_bf16(ah1, cb, acc[1][nf], 0, 0, 0);
        }
    }
    __syncthreads();   // all fragment reads done; smem now reusable

#pragma unroll
    for (int h = 0; h < 2; ++h) {
        if ((wid >> 1) == h) {
            int rbase = (wid & 1) * 32;
#pragma unroll
            for (int mf = 0; mf < 2; ++mf)
#pragma unroll
                for (int nf = 0; nf < 8; ++nf)
#pragma unroll
                    for (int q = 0; q < 4; ++q)
                        out_lds[rbase + mf * 16 + lg * 4 + q][nf * 16 + lr] = acc[mf][nf][q];
        }
        __syncthreads();
#pragma unroll
        for (int rep = 0; rep < 8; ++rep) {        // coalesced float4 stores
            int idx = rep * 256 + tid;
            int r = idx >> 5, c4 = (idx & 31) << 2;
            f32x4 a = *reinterpret_cast<f32x4*>(&out_lds[r][c4]);
            size_t row = (size_t)(m0 + h * 64 + r);
            int c = d0 + c4;
            f32x4 uv = nt_load4(&u[row * DM + c]);
            float4 dv = *reinterpret_cast<const float4*>(&Dv[c]);
            f32x4 o;
            o[0] = a[0] + uv[0] * dv.x;
            o[1] = a[1] + uv[1] * dv.y;
            o[2] = a[2] + uv[2] * dv.z;
            o[3] = a[3] + uv[3] * dv.w;
            nt_store4(&y[row * DM + c], o);
        }
        if (h == 0) __syncthreads();
    }
}

extern "C" void kernel_launch(void* const* d_in, const int* in_sizes, int n_in,
                              void* d_out, int out_size, void* d_ws, size_t ws_size,
                              hipStream_t stream) {
    (void)in_sizes; (void)n_in; (void)out_size; (void)ws_size;
    const float* u      = (const float*)d_in[0];
    const float* A      = (const float*)d_in[1];
    const float* Bm     = (const float*)d_in[2];
    const float* C      = (const float*)d_in[3];
    const float* Dv     = (const float*)d_in[4];
    const float* log_dt = (const float*)d_in[5];
    float* y  = (float*)d_out;
    float* ws = (float*)d_ws;
    float* bu = ws + WS_BU;

    k_setup<<<dim3(129), dim3(256), 0, stream>>>(A, Bm, C, log_dt, ws);
    // A2 kept for the double-step scan; chain ends with A^64 in WS_APOW.
    k_matsq<<<dim3(16), dim3(256), 0, stream>>>(ws + WS_ABAR, ws + WS_A2);    // A^2
    k_matsq<<<dim3(16), dim3(256), 0, stream>>>(ws + WS_A2,   ws + WS_APOW);  // A^4
    k_matsq<<<dim3(16), dim3(256), 0, stream>>>(ws + WS_APOW, ws + WS_TMP);   // A^8
    k_matsq<<<dim3(16), dim3(256), 0, stream>>>(ws + WS_TMP,  ws + WS_APOW);  // A^16
    k_matsq<<<dim3(16), dim3(256), 0, stream>>>(ws + WS_APOW, ws + WS_TMP);   // A^32
    k_matsq<<<dim3(16), dim3(256), 0, stream>>>(ws + WS_TMP,  ws + WS_APOW);  // A^64

    k_gemm1<<<dim3(MTOT / 64), dim3(256), 0, stream>>>(u, ws, bu);
    k_scan<0><<<dim3(NTASK / 4), dim3(256), 0, stream>>>(ws);
    k_combine<<<dim3(NB), dim3(64), 0, stream>>>(ws);
    k_scan<1><<<dim3(NTASK / 4), dim3(256), 0, stream>>>(ws);
    k_gemm2<<<dim3(MTOT / 128, DM / 128), dim3(256), 0, stream>>>(u, Dv, ws, y);
}